// Round 1
// baseline (2772.915 us; speedup 1.0000x reference)
//
#include <hip/hip_runtime.h>
#include <cstdint>

// Problem constants (fixed by the harness inputs)
#define NROWS 8192
#define DM    768
#define DS    16384

// ---------------- Phase 1: pre_relu = relu(x @ W_enc + b_enc) ----------------
// fp32 SGEMM (no fp32 MFMA on CDNA4 -> vector FMA). 128x128 tile, BK=32,
// 256 threads, 8x8 micro-tile per thread. Serial-K fp32 accumulation keeps
// numerical deviation vs the np reference ~1e-7 (top-k swap safety).
#define BM 128
#define BN 128
#define BK 32

__global__ __launch_bounds__(256) void sae_encode_gemm(
    const float* __restrict__ x,    // [NROWS, DM]
    const float* __restrict__ We,   // [DM, DS]
    const float* __restrict__ be,   // [DS]
    float* __restrict__ pre)        // [NROWS, DS] (z region of d_out)
{
  __shared__ float As[BK][BM];      // A stored transposed: As[k][m]
  __shared__ float Bs[BK][BN + 4];  // +4 pad keeps float4 alignment

  const int tid  = threadIdx.x;
  const int bx   = blockIdx.x;            // N tile
  const int by   = blockIdx.y;            // M tile
  const int tcol = (tid & 15) * 8;
  const int trow = (tid >> 4) * 8;

  float acc[8][8];
#pragma unroll
  for (int i = 0; i < 8; ++i)
#pragma unroll
    for (int j = 0; j < 8; ++j) acc[i][j] = 0.f;

  const float* xblk = x  + (size_t)by * BM * DM;
  const float* wblk = We + (size_t)bx * BN;

  for (int k0 = 0; k0 < DM; k0 += BK) {
    // A tile: BM x BK, transposed into LDS. 1024 float4 slots, 4/thread.
#pragma unroll
    for (int i = 0; i < 4; ++i) {
      int s  = tid + i * 256;
      int m  = s >> 3;            // row within tile
      int kk = (s & 7) << 2;      // k within tile (float4)
      float4 v = *(const float4*)(xblk + (size_t)m * DM + (k0 + kk));
      As[kk + 0][m] = v.x;
      As[kk + 1][m] = v.y;
      As[kk + 2][m] = v.z;
      As[kk + 3][m] = v.w;
    }
    // B tile: BK x BN. 1024 float4 slots, 4/thread, coalesced along N.
#pragma unroll
    for (int i = 0; i < 4; ++i) {
      int s  = tid + i * 256;
      int kk = s >> 5;
      int n  = (s & 31) << 2;
      float4 v = *(const float4*)(wblk + (size_t)(k0 + kk) * DS + n);
      *(float4*)&Bs[kk][n] = v;
    }
    __syncthreads();
#pragma unroll 4
    for (int kk = 0; kk < BK; ++kk) {
      float4 a0 = *(const float4*)&As[kk][trow];
      float4 a1 = *(const float4*)&As[kk][trow + 4];
      float4 b0 = *(const float4*)&Bs[kk][tcol];
      float4 b1 = *(const float4*)&Bs[kk][tcol + 4];
      float a[8] = {a0.x, a0.y, a0.z, a0.w, a1.x, a1.y, a1.z, a1.w};
      float b[8] = {b0.x, b0.y, b0.z, b0.w, b1.x, b1.y, b1.z, b1.w};
#pragma unroll
      for (int i = 0; i < 8; ++i)
#pragma unroll
        for (int j = 0; j < 8; ++j) acc[i][j] = fmaf(a[i], b[j], acc[i][j]);
    }
    __syncthreads();
  }

  const int row0 = by * BM + trow;
  const int col0 = bx * BN + tcol;
#pragma unroll
  for (int i = 0; i < 8; ++i) {
    float o[8];
#pragma unroll
    for (int j = 0; j < 8; ++j) o[j] = fmaxf(acc[i][j] + be[col0 + j], 0.f);
    float* dst = pre + (size_t)(row0 + i) * DS + col0;
    *(float4*)dst       = make_float4(o[0], o[1], o[2], o[3]);
    *(float4*)(dst + 4) = make_float4(o[4], o[5], o[6], o[7]);
  }
}

// ---------------- Phase 2: per-row top-k (in place) + sparse decode ----------
// One block per row, 256 threads, 64 elements/thread held in registers as
// uint bit patterns (positive fp32 compare == uint compare; non-positives -> 0,
// and selecting/deselecting zeros is value-identical to the reference).
// k-th largest found by 31-step binary search on bits; ties at the threshold
// broken by lowest index (matches lax.top_k); ordered (idx,val) list built by
// block prefix-scan for a deterministic recon accumulation order.
__global__ __launch_bounds__(256) void sae_topk_decode(
    float* __restrict__ z,          // in: pre_relu, out: z   [NROWS, DS]
    float* __restrict__ recon,      // [NROWS, DM]
    const float* __restrict__ Wd,   // [DS, DM]
    const float* __restrict__ bd,   // [DM]
    const int* __restrict__ kptr)
{
  const int row = blockIdx.x;
  const int tid = threadIdx.x;

  int k = *kptr;
  if (k < 1) k = 1;
  if (k > 1024) k = 1024;   // harness k = 64; list capacity guard

  float* zrow = z + (size_t)row * DS;

  unsigned u[64];
  {
    const float4* src = (const float4*)zrow;
#pragma unroll
    for (int jj = 0; jj < 16; ++jj) {
      float4 v = src[tid + jj * 256];
      u[jj * 4 + 0] = (v.x > 0.f) ? __float_as_uint(v.x) : 0u;
      u[jj * 4 + 1] = (v.y > 0.f) ? __float_as_uint(v.y) : 0u;
      u[jj * 4 + 2] = (v.z > 0.f) ? __float_as_uint(v.z) : 0u;
      u[jj * 4 + 3] = (v.w > 0.f) ? __float_as_uint(v.w) : 0u;
    }
  }

  __shared__ int red[8];

  // ---- binary search for tbits = bit pattern of k-th largest value ----
  unsigned tbits = 0;
  for (int bit = 30; bit >= 0; --bit) {
    unsigned cand = tbits | (1u << bit);
    int c = 0;
#pragma unroll
    for (int j = 0; j < 64; ++j) c += (u[j] >= cand);
#pragma unroll
    for (int off = 32; off > 0; off >>= 1) c += __shfl_down(c, off, 64);
    if ((tid & 63) == 0) red[tid >> 6] = c;
    __syncthreads();
    int tot = red[0] + red[1] + red[2] + red[3];
    __syncthreads();
    if (tot >= k) tbits = cand;   // uniform across block
  }

  // ---- counts at the threshold ----
  int cnt_gt = 0, cnt_eq = 0;
  if (tbits != 0) {
    int c1 = 0, c2 = 0;
#pragma unroll
    for (int j = 0; j < 64; ++j) { c1 += (u[j] > tbits); c2 += (u[j] == tbits); }
#pragma unroll
    for (int off = 32; off > 0; off >>= 1) {
      c1 += __shfl_down(c1, off, 64);
      c2 += __shfl_down(c2, off, 64);
    }
    if ((tid & 63) == 0) { red[tid >> 6] = c1; red[4 + (tid >> 6)] = c2; }
    __syncthreads();
    cnt_gt = red[0] + red[1] + red[2] + red[3];
    cnt_eq = red[4] + red[5] + red[6] + red[7];
    __syncthreads();
  }
  const int needed = k - cnt_gt;

  // ---- rare path: duplicated values exactly at the threshold ----
  __shared__ int eq_n;
  __shared__ int eq_keep;
  __shared__ int eq_idx[256];
  const bool rare = (tbits != 0) && (cnt_eq > needed);
  if (rare) {
    if (tid == 0) eq_n = 0;
    __syncthreads();
#pragma unroll
    for (int jj = 0; jj < 16; ++jj)
#pragma unroll
      for (int c = 0; c < 4; ++c) {
        int j = jj * 4 + c;
        if (u[j] == tbits) {
          int p = atomicAdd(&eq_n, 1);
          if (p < 256) eq_idx[p] = (tid + jj * 256) * 4 + c;
        }
      }
    __syncthreads();
    if (tid == 0) {
      int n = eq_n < 256 ? eq_n : 256;
      for (int a = 1; a < n; ++a) {          // insertion sort ascending (tiny)
        int key = eq_idx[a]; int b = a - 1;
        while (b >= 0 && eq_idx[b] > key) { eq_idx[b + 1] = eq_idx[b]; --b; }
        eq_idx[b + 1] = key;
      }
      int kp = needed < n ? needed : n;
      eq_keep = kp < 0 ? 0 : kp;
    }
    __syncthreads();
  }

  // ---- build selection mask ----
  unsigned long long mask = 0ull;
#pragma unroll
  for (int jj = 0; jj < 16; ++jj)
#pragma unroll
    for (int c = 0; c < 4; ++c) {
      int j = jj * 4 + c;
      bool sel;
      if (tbits == 0) {
        sel = (u[j] > 0u);                  // fewer than k positives: zeros are no-ops
      } else if (u[j] > tbits) {
        sel = true;
      } else if (u[j] == tbits) {
        if (!rare) sel = true;
        else {
          int idx = (tid + jj * 256) * 4 + c;
          sel = false;
          for (int e = 0; e < eq_keep; ++e)
            if (eq_idx[e] == idx) { sel = true; break; }
        }
      } else sel = false;
      if (sel) mask |= (1ull << j);
    }
  const int mycount = __popcll(mask);

  // ---- deterministic ordered list via block prefix scan ----
  __shared__ int scan[256];
  scan[tid] = mycount;
  __syncthreads();
  for (int off = 1; off < 256; off <<= 1) {
    int v = scan[tid];
    int add = (tid >= off) ? scan[tid - off] : 0;
    __syncthreads();
    scan[tid] = v + add;
    __syncthreads();
  }
  const int total = scan[255];
  int pos = scan[tid] - mycount;

  // ---- emit list + write z row (in place) ----
  __shared__ float s_val[1024];
  __shared__ int   s_idx[1024];
  {
    float4* dst = (float4*)zrow;
#pragma unroll
    for (int jj = 0; jj < 16; ++jj) {
      float4 w;
      float* wp = (float*)&w;
#pragma unroll
      for (int c = 0; c < 4; ++c) {
        int j = jj * 4 + c;
        bool s = (mask >> j) & 1ull;
        float val = __uint_as_float(u[j]);
        wp[c] = s ? val : 0.f;
        if (s && pos < 1024) {
          s_idx[pos] = (tid + jj * 256) * 4 + c;
          s_val[pos] = val;
          ++pos;
        }
      }
      dst[tid + jj * 256] = w;
    }
  }
  __syncthreads();

  // ---- sparse decode: recon = sum_i val_i * W_dec[idx_i, :] + b_dec ----
  float a0 = bd[tid], a1 = bd[tid + 256], a2 = bd[tid + 512];
  const int n = total < 1024 ? total : 1024;
#pragma unroll 4
  for (int i = 0; i < n; ++i) {
    float v = s_val[i];
    const float* wr = Wd + (size_t)s_idx[i] * DM;
    a0 = fmaf(v, wr[tid],       a0);
    a1 = fmaf(v, wr[tid + 256], a1);
    a2 = fmaf(v, wr[tid + 512], a2);
  }
  float* rr = recon + (size_t)row * DM;
  rr[tid] = a0; rr[tid + 256] = a1; rr[tid + 512] = a2;
}

// ------------------------------------------------------------------------------
extern "C" void kernel_launch(void* const* d_in, const int* in_sizes, int n_in,
                              void* d_out, int out_size, void* d_ws, size_t ws_size,
                              hipStream_t stream) {
  (void)in_sizes; (void)n_in; (void)out_size; (void)d_ws; (void)ws_size;

  const float* x     = (const float*)d_in[0];
  const float* W_enc = (const float*)d_in[1];
  const float* b_enc = (const float*)d_in[2];
  const float* W_dec = (const float*)d_in[3];
  const float* b_dec = (const float*)d_in[4];
  const int*   kp    = (const int*)d_in[5];

  float* z     = (float*)d_out;                    // [NROWS, DS]
  float* recon = z + (size_t)NROWS * DS;           // [NROWS, DM]

  dim3 g1(DS / BN, NROWS / BM);                    // (128, 64)
  sae_encode_gemm<<<g1, 256, 0, stream>>>(x, W_enc, b_enc, z);
  sae_topk_decode<<<NROWS, 256, 0, stream>>>(z, recon, W_dec, b_dec, kp);
}

// Round 2
// 2629.993 us; speedup vs baseline: 1.0543x; 1.0543x over previous
//
#include <hip/hip_runtime.h>
#include <cstdint>

// Problem constants (fixed by the harness inputs)
#define NROWS 8192
#define DM    768
#define DS    16384

// ---------------- Phase 1: pre_relu = relu(x @ W_enc + b_enc) ----------------
// fp32 SGEMM (no fp32 MFMA on CDNA4 -> vector FMA). 128x128 tile, BK=32,
// 256 threads. R1 change: bank-conflict-free LDS scheme.
//   * micro-tile = 4x4 fragments in a 2x2 spread (rows r0/r0+64, cols c0/c0+64)
//     -> B-frag reads 2-way (free), A-frag reads conflict-free.
//   * A stored transposed with XOR swizzle col' = m ^ (kk & 0x1C), stride 128
//     -> transpose writes 2-way (were 8-way). Swizzle only touches bits 2-4 so
//     float4 fragment reads stay contiguous ((r0^kkm)+j, j=0..3).
#define BM 128
#define BN 128
#define BK 32

__global__ __launch_bounds__(256) void sae_encode_gemm(
    const float* __restrict__ x,    // [NROWS, DM]
    const float* __restrict__ We,   // [DM, DS]
    const float* __restrict__ be,   // [DS]
    float* __restrict__ pre)        // [NROWS, DS] (z region of d_out)
{
  __shared__ float As[BK][BM];      // logical (kk, m) stored at As[kk][m ^ (kk & 0x1C)]
  __shared__ float Bs[BK][BN];      // row-major, no pad needed (reads are 2-way free)

  const int tid = threadIdx.x;
  const int bx  = blockIdx.x;             // N tile
  const int by  = blockIdx.y;             // M tile
  const int c0  = (tid & 15) * 4;          // col fragment base (plus +64 block)
  const int r0  = (tid >> 4) * 4;          // row fragment base (plus +64 block)

  float acc[2][2][4][4];
#pragma unroll
  for (int p = 0; p < 2; ++p)
#pragma unroll
    for (int q = 0; q < 2; ++q)
#pragma unroll
      for (int i = 0; i < 4; ++i)
#pragma unroll
        for (int j = 0; j < 4; ++j) acc[p][q][i][j] = 0.f;

  const float* xblk = x  + (size_t)by * BM * DM;
  const float* wblk = We + (size_t)bx * BN;

  for (int k0 = 0; k0 < DM; k0 += BK) {
    // A tile: BM x BK, transposed + swizzled into LDS. 1024 float4 loads total.
#pragma unroll
    for (int i = 0; i < 4; ++i) {
      int s   = tid + i * 256;
      int m   = s >> 3;             // row within tile (0..127)
      int kk4 = (s & 7) << 2;       // k within tile, multiple of 4
      float4 v = *(const float4*)(xblk + (size_t)m * DM + (k0 + kk4));
      int cs = m ^ kk4;             // kk4 == (kk & 0x1C) for kk in [kk4, kk4+3]
      As[kk4 + 0][cs] = v.x;
      As[kk4 + 1][cs] = v.y;
      As[kk4 + 2][cs] = v.z;
      As[kk4 + 3][cs] = v.w;
    }
    // B tile: BK x BN, coalesced float4, linear layout.
#pragma unroll
    for (int i = 0; i < 4; ++i) {
      int s  = tid + i * 256;
      int kk = s >> 5;
      int n  = (s & 31) << 2;
      *(float4*)&Bs[kk][n] = *(const float4*)(wblk + (size_t)(k0 + kk) * DS + n);
    }
    __syncthreads();

#pragma unroll 4
    for (int kk = 0; kk < BK; ++kk) {
      const int kkm = kk & 0x1C;
      const int ra  = r0 ^ kkm;
      float4 a0 = *(const float4*)&As[kk][ra];
      float4 a1 = *(const float4*)&As[kk][ra + 64];
      float4 b0 = *(const float4*)&Bs[kk][c0];
      float4 b1 = *(const float4*)&Bs[kk][c0 + 64];
      float av[2][4] = {{a0.x, a0.y, a0.z, a0.w}, {a1.x, a1.y, a1.z, a1.w}};
      float bv[2][4] = {{b0.x, b0.y, b0.z, b0.w}, {b1.x, b1.y, b1.z, b1.w}};
#pragma unroll
      for (int p = 0; p < 2; ++p)
#pragma unroll
        for (int q = 0; q < 2; ++q)
#pragma unroll
          for (int i = 0; i < 4; ++i)
#pragma unroll
            for (int j = 0; j < 4; ++j)
              acc[p][q][i][j] = fmaf(av[p][i], bv[q][j], acc[p][q][i][j]);
    }
    __syncthreads();
  }

  // Epilogue: bias + relu + store
  const int row0 = by * BM + r0;
  const int col0 = bx * BN + c0;
  float bias[2][4];
#pragma unroll
  for (int q = 0; q < 2; ++q)
#pragma unroll
    for (int j = 0; j < 4; ++j) bias[q][j] = be[col0 + q * 64 + j];

#pragma unroll
  for (int p = 0; p < 2; ++p)
#pragma unroll
    for (int i = 0; i < 4; ++i) {
      float* dst = pre + (size_t)(row0 + p * 64 + i) * DS + col0;
#pragma unroll
      for (int q = 0; q < 2; ++q) {
        float4 o;
        o.x = fmaxf(acc[p][q][i][0] + bias[q][0], 0.f);
        o.y = fmaxf(acc[p][q][i][1] + bias[q][1], 0.f);
        o.z = fmaxf(acc[p][q][i][2] + bias[q][2], 0.f);
        o.w = fmaxf(acc[p][q][i][3] + bias[q][3], 0.f);
        *(float4*)(dst + q * 64) = o;
      }
    }
}

// ---------------- Phase 2: per-row top-k (in place) + sparse decode ----------
// One block per row, 256 threads, 64 elements/thread held in registers as
// uint bit patterns (positive fp32 compare == uint compare; non-positives -> 0,
// and selecting/deselecting zeros is value-identical to the reference).
// k-th largest found by 31-step binary search on bits; ties at the threshold
// broken by lowest index (matches lax.top_k); ordered (idx,val) list built by
// block prefix-scan for a deterministic recon accumulation order.
__global__ __launch_bounds__(256) void sae_topk_decode(
    float* __restrict__ z,          // in: pre_relu, out: z   [NROWS, DS]
    float* __restrict__ recon,      // [NROWS, DM]
    const float* __restrict__ Wd,   // [DS, DM]
    const float* __restrict__ bd,   // [DM]
    const int* __restrict__ kptr)
{
  const int row = blockIdx.x;
  const int tid = threadIdx.x;

  int k = *kptr;
  if (k < 1) k = 1;
  if (k > 1024) k = 1024;   // harness k = 64; list capacity guard

  float* zrow = z + (size_t)row * DS;

  unsigned u[64];
  {
    const float4* src = (const float4*)zrow;
#pragma unroll
    for (int jj = 0; jj < 16; ++jj) {
      float4 v = src[tid + jj * 256];
      u[jj * 4 + 0] = (v.x > 0.f) ? __float_as_uint(v.x) : 0u;
      u[jj * 4 + 1] = (v.y > 0.f) ? __float_as_uint(v.y) : 0u;
      u[jj * 4 + 2] = (v.z > 0.f) ? __float_as_uint(v.z) : 0u;
      u[jj * 4 + 3] = (v.w > 0.f) ? __float_as_uint(v.w) : 0u;
    }
  }

  __shared__ int red[8];

  // ---- binary search for tbits = bit pattern of k-th largest value ----
  unsigned tbits = 0;
  for (int bit = 30; bit >= 0; --bit) {
    unsigned cand = tbits | (1u << bit);
    int c = 0;
#pragma unroll
    for (int j = 0; j < 64; ++j) c += (u[j] >= cand);
#pragma unroll
    for (int off = 32; off > 0; off >>= 1) c += __shfl_down(c, off, 64);
    if ((tid & 63) == 0) red[tid >> 6] = c;
    __syncthreads();
    int tot = red[0] + red[1] + red[2] + red[3];
    __syncthreads();
    if (tot >= k) tbits = cand;   // uniform across block
  }

  // ---- counts at the threshold ----
  int cnt_gt = 0, cnt_eq = 0;
  if (tbits != 0) {
    int c1 = 0, c2 = 0;
#pragma unroll
    for (int j = 0; j < 64; ++j) { c1 += (u[j] > tbits); c2 += (u[j] == tbits); }
#pragma unroll
    for (int off = 32; off > 0; off >>= 1) {
      c1 += __shfl_down(c1, off, 64);
      c2 += __shfl_down(c2, off, 64);
    }
    if ((tid & 63) == 0) { red[tid >> 6] = c1; red[4 + (tid >> 6)] = c2; }
    __syncthreads();
    cnt_gt = red[0] + red[1] + red[2] + red[3];
    cnt_eq = red[4] + red[5] + red[6] + red[7];
    __syncthreads();
  }
  const int needed = k - cnt_gt;

  // ---- rare path: duplicated values exactly at the threshold ----
  __shared__ int eq_n;
  __shared__ int eq_keep;
  __shared__ int eq_idx[256];
  const bool rare = (tbits != 0) && (cnt_eq > needed);
  if (rare) {
    if (tid == 0) eq_n = 0;
    __syncthreads();
#pragma unroll
    for (int jj = 0; jj < 16; ++jj)
#pragma unroll
      for (int c = 0; c < 4; ++c) {
        int j = jj * 4 + c;
        if (u[j] == tbits) {
          int p = atomicAdd(&eq_n, 1);
          if (p < 256) eq_idx[p] = (tid + jj * 256) * 4 + c;
        }
      }
    __syncthreads();
    if (tid == 0) {
      int n = eq_n < 256 ? eq_n : 256;
      for (int a = 1; a < n; ++a) {          // insertion sort ascending (tiny)
        int key = eq_idx[a]; int b = a - 1;
        while (b >= 0 && eq_idx[b] > key) { eq_idx[b + 1] = eq_idx[b]; --b; }
        eq_idx[b + 1] = key;
      }
      int kp = needed < n ? needed : n;
      eq_keep = kp < 0 ? 0 : kp;
    }
    __syncthreads();
  }

  // ---- build selection mask ----
  unsigned long long mask = 0ull;
#pragma unroll
  for (int jj = 0; jj < 16; ++jj)
#pragma unroll
    for (int c = 0; c < 4; ++c) {
      int j = jj * 4 + c;
      bool sel;
      if (tbits == 0) {
        sel = (u[j] > 0u);                  // fewer than k positives: zeros are no-ops
      } else if (u[j] > tbits) {
        sel = true;
      } else if (u[j] == tbits) {
        if (!rare) sel = true;
        else {
          int idx = (tid + jj * 256) * 4 + c;
          sel = false;
          for (int e = 0; e < eq_keep; ++e)
            if (eq_idx[e] == idx) { sel = true; break; }
        }
      } else sel = false;
      if (sel) mask |= (1ull << j);
    }
  const int mycount = __popcll(mask);

  // ---- deterministic ordered list via block prefix scan ----
  __shared__ int scan[256];
  scan[tid] = mycount;
  __syncthreads();
  for (int off = 1; off < 256; off <<= 1) {
    int v = scan[tid];
    int add = (tid >= off) ? scan[tid - off] : 0;
    __syncthreads();
    scan[tid] = v + add;
    __syncthreads();
  }
  const int total = scan[255];
  int pos = scan[tid] - mycount;

  // ---- emit list + write z row (in place) ----
  __shared__ float s_val[1024];
  __shared__ int   s_idx[1024];
  {
    float4* dst = (float4*)zrow;
#pragma unroll
    for (int jj = 0; jj < 16; ++jj) {
      float4 w;
      float* wp = (float*)&w;
#pragma unroll
      for (int c = 0; c < 4; ++c) {
        int j = jj * 4 + c;
        bool s = (mask >> j) & 1ull;
        float val = __uint_as_float(u[j]);
        wp[c] = s ? val : 0.f;
        if (s && pos < 1024) {
          s_idx[pos] = (tid + jj * 256) * 4 + c;
          s_val[pos] = val;
          ++pos;
        }
      }
      dst[tid + jj * 256] = w;
    }
  }
  __syncthreads();

  // ---- sparse decode: recon = sum_i val_i * W_dec[idx_i, :] + b_dec ----
  float a0 = bd[tid], a1 = bd[tid + 256], a2 = bd[tid + 512];
  const int n = total < 1024 ? total : 1024;
#pragma unroll 4
  for (int i = 0; i < n; ++i) {
    float v = s_val[i];
    const float* wr = Wd + (size_t)s_idx[i] * DM;
    a0 = fmaf(v, wr[tid],       a0);
    a1 = fmaf(v, wr[tid + 256], a1);
    a2 = fmaf(v, wr[tid + 512], a2);
  }
  float* rr = recon + (size_t)row * DM;
  rr[tid] = a0; rr[tid + 256] = a1; rr[tid + 512] = a2;
}

// ------------------------------------------------------------------------------
extern "C" void kernel_launch(void* const* d_in, const int* in_sizes, int n_in,
                              void* d_out, int out_size, void* d_ws, size_t ws_size,
                              hipStream_t stream) {
  (void)in_sizes; (void)n_in; (void)out_size; (void)d_ws; (void)ws_size;

  const float* x     = (const float*)d_in[0];
  const float* W_enc = (const float*)d_in[1];
  const float* b_enc = (const float*)d_in[2];
  const float* W_dec = (const float*)d_in[3];
  const float* b_dec = (const float*)d_in[4];
  const int*   kp    = (const int*)d_in[5];

  float* z     = (float*)d_out;                    // [NROWS, DS]
  float* recon = z + (size_t)NROWS * DS;           // [NROWS, DM]

  dim3 g1(DS / BN, NROWS / BM);                    // (128, 64)
  sae_encode_gemm<<<g1, 256, 0, stream>>>(x, W_enc, b_enc, z);
  sae_topk_decode<<<NROWS, 256, 0, stream>>>(z, recon, W_dec, b_dec, kp);
}

// Round 4
// 1290.164 us; speedup vs baseline: 2.1493x; 2.0385x over previous
//
#include <hip/hip_runtime.h>
#include <cstdint>

// Problem constants (fixed by the harness inputs)
#define NROWS 8192
#define DM    768
#define DS    16384

typedef __attribute__((ext_vector_type(8))) short          bf16x8;
typedef __attribute__((ext_vector_type(8))) unsigned short u16x8;
typedef __attribute__((ext_vector_type(4))) float          f32x4;

__device__ __forceinline__ unsigned short f2bf(float f) {
  unsigned u = __float_as_uint(f);
  unsigned r = u + 0x7fffu + ((u >> 16) & 1u);   // RNE
  return (unsigned short)(r >> 16);
}

// ======================= FAST PATH (needs 88MB workspace) =======================

// ---- prep 1: x fp32 -> bf16 ----
__global__ __launch_bounds__(256) void cvt_x_bf16(const float* __restrict__ x,
                                                  unsigned short* __restrict__ xb) {
  int i = blockIdx.x * 256 + threadIdx.x;        // float4 index; grid covers exactly
  float4 v = ((const float4*)x)[i];
  ushort4 o;
  o.x = f2bf(v.x); o.y = f2bf(v.y); o.z = f2bf(v.z); o.w = f2bf(v.w);
  ((ushort4*)xb)[i] = o;
}

// ---- prep 2: W_enc [DM][DS] -> WTf fp32 [DS][DM] + WTb bf16 [DS][DM] ----
__global__ __launch_bounds__(256) void transpose_w(const float* __restrict__ We,
                                                   float* __restrict__ WTf,
                                                   unsigned short* __restrict__ WTb) {
  __shared__ float t[32][33];
  const int c0 = blockIdx.x * 32;   // DS dim
  const int r0 = blockIdx.y * 32;   // DM dim
  const int tx = threadIdx.x & 31, ty = threadIdx.x >> 5;  // ty 0..7
#pragma unroll
  for (int i = 0; i < 4; ++i)
    t[ty + i * 8][tx] = We[(size_t)(r0 + ty + i * 8) * DS + c0 + tx];
  __syncthreads();
#pragma unroll
  for (int i = 0; i < 4; ++i) {
    float v = t[tx][ty + i * 8];
    size_t o = (size_t)(c0 + ty + i * 8) * DM + r0 + tx;
    WTf[o] = v;
    WTb[o] = f2bf(v);
  }
}

// ---- approx encode: pre = x_bf16 @ Wenc_bf16 + b_enc (RAW, no relu) ----
// 128x128 tile, BK=64, 4 waves (2x2), per-wave 64x64 via 4x4 frags of
// mfma_f32_16x16x32_bf16. LDS [row][64k] bf16 with T2 XOR swizzle on the
// 16B k-granule: byte(row,k) = row*128 + (((k>>3) ^ (row&7))<<4) + (k&7)*2.
// Accuracy only needs to be within the prune margin (16e-3 ~ 13 sigma of the
// bf16 dot-error model) -- selection correctness comes from the exact stage.
__global__ __launch_bounds__(256) void sae_encode_bf16(
    const unsigned short* __restrict__ xb,   // [NROWS][DM] bf16
    const unsigned short* __restrict__ WTb,  // [DS][DM] bf16 (W_enc^T)
    const float* __restrict__ be,            // [DS]
    float* __restrict__ pre)                 // [NROWS][DS] raw approx
{
  __shared__ __align__(16) short As[128 * 64];
  __shared__ __align__(16) short Bs[128 * 64];

  const int tid  = threadIdx.x;
  const int lane = tid & 63;
  const int w    = tid >> 6;          // wave 0..3
  const int wm   = w >> 1, wn = w & 1;
  const int m0   = blockIdx.y * 128, n0 = blockIdx.x * 128;
  const int l15  = lane & 15, q = lane >> 4, l7 = lane & 7;

  f32x4 acc[4][4];
  const f32x4 zero4 = {0.f, 0.f, 0.f, 0.f};
#pragma unroll
  for (int i = 0; i < 4; ++i)
#pragma unroll
    for (int j = 0; j < 4; ++j) acc[i][j] = zero4;

  for (int k0 = 0; k0 < DM; k0 += 64) {
    // stage A (x rows) and B (WencT rows): 1024 16B-granules each, 4/thread
#pragma unroll
    for (int i = 0; i < 4; ++i) {
      int idx = tid + i * 256;
      int m = idx >> 3, g = idx & 7;
      int ldsb = m * 128 + (((g ^ (m & 7))) << 4);
      u16x8 va = *(const u16x8*)(xb  + (size_t)(m0 + m) * DM + k0 + g * 8);
      *(u16x8*)((char*)As + ldsb) = va;
      u16x8 vb = *(const u16x8*)(WTb + (size_t)(n0 + m) * DM + k0 + g * 8);
      *(u16x8*)((char*)Bs + ldsb) = vb;
    }
    __syncthreads();

#pragma unroll
    for (int h = 0; h < 2; ++h) {
      const int gsw = (((h * 4 + q) ^ l7) << 4);
      bf16x8 af[4], bfr[4];
#pragma unroll
      for (int t = 0; t < 4; ++t) {
        af[t]  = *(const bf16x8*)((const char*)As + (wm * 64 + t * 16 + l15) * 128 + gsw);
        bfr[t] = *(const bf16x8*)((const char*)Bs + (wn * 64 + t * 16 + l15) * 128 + gsw);
      }
#pragma unroll
      for (int mf = 0; mf < 4; ++mf)
#pragma unroll
        for (int nf = 0; nf < 4; ++nf)
          acc[mf][nf] = __builtin_amdgcn_mfma_f32_16x16x32_bf16(
              af[mf], bfr[nf], acc[mf][nf], 0, 0, 0);
    }
    __syncthreads();
  }

  // epilogue: D layout col = lane&15, row = (lane>>4)*4 + r  [m89]
#pragma unroll
  for (int nf = 0; nf < 4; ++nf) {
    const int gcol = n0 + wn * 64 + nf * 16 + l15;
    const float bias = be[gcol];
#pragma unroll
    for (int mf = 0; mf < 4; ++mf) {
#pragma unroll
      for (int r = 0; r < 4; ++r) {
        int grow = m0 + wm * 64 + mf * 16 + q * 4 + r;
        pre[(size_t)grow * DS + gcol] = acc[mf][nf][r] + bias;
      }
    }
  }
}

// ---- per-row: approx top-k -> candidates -> exact recompute in R2's EXACT
//      summation order (serial k=0..767 fmaf chain, then +bias, then relu).
//      This makes the final ranking bit-identical to the R2 kernel that
//      passed the harness -- no new fp32-ordering lottery at rank-64 ties.
#define MARGIN  1.6e-2f
#define MAXCAND 256

__global__ __launch_bounds__(256) void sae_topk_exact(
    float* __restrict__ z,            // in: raw approx; out: z  [NROWS][DS]
    float* __restrict__ recon,        // [NROWS][DM]
    const float* __restrict__ x,      // fp32 [NROWS][DM]
    const float* __restrict__ WTf,    // fp32 [DS][DM] (W_enc^T)
    const float* __restrict__ be,     // [DS]
    const float* __restrict__ Wd,     // [DS][DM]
    const float* __restrict__ bd,     // [DM]
    const int* __restrict__ kptr)
{
  const int row = blockIdx.x;
  const int tid = threadIdx.x;
  int k = *kptr; if (k < 1) k = 1; if (k > 128) k = 128;  // harness k = 64

  float* zrow = z + (size_t)row * DS;

  __shared__ int   red[4];
  __shared__ float xs[DM];
  __shared__ int   cidx[MAXCAND];
  __shared__ float cex[MAXCAND];
  __shared__ int   s_n;
  __shared__ int   sidx[128];
  __shared__ float sval[128];

  // relu'd approx as uint bit patterns (positive f32 compare == uint compare)
  unsigned u[64];
  {
    const float4* src = (const float4*)zrow;
#pragma unroll
    for (int jj = 0; jj < 16; ++jj) {
      float4 v = src[tid + jj * 256];
      u[jj * 4 + 0] = (v.x > 0.f) ? __float_as_uint(v.x) : 0u;
      u[jj * 4 + 1] = (v.y > 0.f) ? __float_as_uint(v.y) : 0u;
      u[jj * 4 + 2] = (v.z > 0.f) ? __float_as_uint(v.z) : 0u;
      u[jj * 4 + 3] = (v.w > 0.f) ? __float_as_uint(v.w) : 0u;
    }
  }
  // x row -> LDS (exact-recompute operand); covered by the search's barriers
  for (int i = tid; i < DM; i += 256) xs[i] = x[(size_t)row * DM + i];
  if (tid == 0) s_n = 0;

  // binary search for bit pattern of approx k-th largest (relu'd)
  unsigned tbits = 0;
  for (int bit = 30; bit >= 0; --bit) {
    unsigned cand = tbits | (1u << bit);
    int c = 0;
#pragma unroll
    for (int j = 0; j < 64; ++j) c += (u[j] >= cand);
#pragma unroll
    for (int off = 32; off > 0; off >>= 1) c += __shfl_down(c, off, 64);
    if ((tid & 63) == 0) red[tid >> 6] = c;
    __syncthreads();
    int tot = red[0] + red[1] + red[2] + red[3];
    __syncthreads();
    if (tot >= k) tbits = cand;   // uniform across block
  }

  // candidate threshold: (approx v_k) - margin, clamped at 0
  const float thrf = __uint_as_float(tbits) - MARGIN;
  const unsigned tb = (thrf > 0.f) ? __float_as_uint(thrf) : 0u;

#pragma unroll
  for (int jj = 0; jj < 16; ++jj)
#pragma unroll
    for (int c = 0; c < 4; ++c) {
      int j = jj * 4 + c;
      if (u[j] > tb) {
        int p = atomicAdd(&s_n, 1);
        if (p < MAXCAND) cidx[p] = (tid + jj * 256) * 4 + c;
      }
    }
  __syncthreads();
  const int ncand = (s_n < MAXCAND) ? s_n : MAXCAND;

  // exact fp32 recompute, thread-per-candidate, serial k ascending.
  // fmaf chain order == R2 GEMM's accumulation order -> bit-identical values.
  // wcol walk is per-thread sequential (16 floats per 64B line); WTf is
  // L3-resident (50MB), so the uncoalesced gather is cache-served.
  for (int c = tid; c < ncand; c += 256) {
    const float* wcol = WTf + (size_t)cidx[c] * DM;
    float s = 0.f;
#pragma unroll 8
    for (int i = 0; i < DM; ++i) s = fmaf(xs[i], wcol[i], s);
    cex[c] = s + be[cidx[c]];
  }
  __syncthreads();

  const int kk = (k < ncand) ? k : ncand;

  // exact ranking (val desc, idx asc) -> slots
  if (tid < ncand) {
    const float er  = fmaxf(cex[tid], 0.f);
    const int   myi = cidx[tid];
    int rank = 0;
    for (int c = 0; c < ncand; ++c) {
      float ec = fmaxf(cex[c], 0.f);
      rank += (ec > er) || (ec == er && cidx[c] < myi);
    }
    if (rank < kk) { sidx[rank] = myi; sval[rank] = er; }
  }
  __syncthreads();

  // zero z row, then scatter exact top-k
  {
    float4 z4 = make_float4(0.f, 0.f, 0.f, 0.f);
    float4* dst = (float4*)zrow;
#pragma unroll
    for (int jj = 0; jj < 16; ++jj) dst[tid + jj * 256] = z4;
  }
  __syncthreads();
  if (tid < kk && sval[tid] > 0.f) zrow[sidx[tid]] = sval[tid];

  // sparse decode: recon = sum_r sval[r] * W_dec[sidx[r],:] + b_dec
  float a0 = bd[tid], a1 = bd[tid + 256], a2 = bd[tid + 512];
  for (int r = 0; r < kk; ++r) {
    float v = sval[r];
    if (v > 0.f) {
      const float* wr = Wd + (size_t)sidx[r] * DM;
      a0 = fmaf(v, wr[tid],       a0);
      a1 = fmaf(v, wr[tid + 256], a1);
      a2 = fmaf(v, wr[tid + 512], a2);
    }
  }
  float* rr = recon + (size_t)row * DM;
  rr[tid] = a0; rr[tid + 256] = a1; rr[tid + 512] = a2;
}

// ======================= FALLBACK PATH (R2, proven) =======================
#define BM 128
#define BN 128
#define BK 32

__global__ __launch_bounds__(256) void sae_encode_gemm(
    const float* __restrict__ x, const float* __restrict__ We,
    const float* __restrict__ be, float* __restrict__ pre)
{
  __shared__ float As2[BK][BM];
  __shared__ float Bs2[BK][BN];

  const int tid = threadIdx.x;
  const int bx  = blockIdx.x;
  const int by  = blockIdx.y;
  const int c0  = (tid & 15) * 4;
  const int r0  = (tid >> 4) * 4;

  float acc[2][2][4][4];
#pragma unroll
  for (int p = 0; p < 2; ++p)
#pragma unroll
    for (int qq = 0; qq < 2; ++qq)
#pragma unroll
      for (int i = 0; i < 4; ++i)
#pragma unroll
        for (int j = 0; j < 4; ++j) acc[p][qq][i][j] = 0.f;

  const float* xblk = x  + (size_t)by * BM * DM;
  const float* wblk = We + (size_t)bx * BN;

  for (int k0 = 0; k0 < DM; k0 += BK) {
#pragma unroll
    for (int i = 0; i < 4; ++i) {
      int s  = tid + i * 256;
      int m  = s >> 3;
      int kk4 = (s & 7) << 2;
      float4 v = *(const float4*)(xblk + (size_t)m * DM + (k0 + kk4));
      int cs = m ^ kk4;
      As2[kk4 + 0][cs] = v.x;
      As2[kk4 + 1][cs] = v.y;
      As2[kk4 + 2][cs] = v.z;
      As2[kk4 + 3][cs] = v.w;
    }
#pragma unroll
    for (int i = 0; i < 4; ++i) {
      int s  = tid + i * 256;
      int kk = s >> 5;
      int n  = (s & 31) << 2;
      *(float4*)&Bs2[kk][n] = *(const float4*)(wblk + (size_t)(k0 + kk) * DS + n);
    }
    __syncthreads();
#pragma unroll 4
    for (int kk = 0; kk < BK; ++kk) {
      const int kkm = kk & 0x1C;
      const int ra  = r0 ^ kkm;
      float4 a0 = *(const float4*)&As2[kk][ra];
      float4 a1 = *(const float4*)&As2[kk][ra + 64];
      float4 b0 = *(const float4*)&Bs2[kk][c0];
      float4 b1 = *(const float4*)&Bs2[kk][c0 + 64];
      float av[2][4] = {{a0.x, a0.y, a0.z, a0.w}, {a1.x, a1.y, a1.z, a1.w}};
      float bv[2][4] = {{b0.x, b0.y, b0.z, b0.w}, {b1.x, b1.y, b1.z, b1.w}};
#pragma unroll
      for (int p = 0; p < 2; ++p)
#pragma unroll
        for (int qq = 0; qq < 2; ++qq)
#pragma unroll
          for (int i = 0; i < 4; ++i)
#pragma unroll
            for (int j = 0; j < 4; ++j)
              acc[p][qq][i][j] = fmaf(av[p][i], bv[qq][j], acc[p][qq][i][j]);
    }
    __syncthreads();
  }

  const int row0 = by * BM + r0;
  const int col0 = bx * BN + c0;
  float bias[2][4];
#pragma unroll
  for (int qq = 0; qq < 2; ++qq)
#pragma unroll
    for (int j = 0; j < 4; ++j) bias[qq][j] = be[col0 + qq * 64 + j];
#pragma unroll
  for (int p = 0; p < 2; ++p)
#pragma unroll
    for (int i = 0; i < 4; ++i) {
      float* dst = pre + (size_t)(row0 + p * 64 + i) * DS + col0;
#pragma unroll
      for (int qq = 0; qq < 2; ++qq) {
        float4 o;
        o.x = fmaxf(acc[p][qq][i][0] + bias[qq][0], 0.f);
        o.y = fmaxf(acc[p][qq][i][1] + bias[qq][1], 0.f);
        o.z = fmaxf(acc[p][qq][i][2] + bias[qq][2], 0.f);
        o.w = fmaxf(acc[p][qq][i][3] + bias[qq][3], 0.f);
        *(float4*)(dst + qq * 64) = o;
      }
    }
}

__global__ __launch_bounds__(256) void sae_topk_decode(
    float* __restrict__ z, float* __restrict__ recon,
    const float* __restrict__ Wd, const float* __restrict__ bd,
    const int* __restrict__ kptr)
{
  const int row = blockIdx.x;
  const int tid = threadIdx.x;
  int k = *kptr;
  if (k < 1) k = 1;
  if (k > 1024) k = 1024;

  float* zrow = z + (size_t)row * DS;

  unsigned u[64];
  {
    const float4* src = (const float4*)zrow;
#pragma unroll
    for (int jj = 0; jj < 16; ++jj) {
      float4 v = src[tid + jj * 256];
      u[jj * 4 + 0] = (v.x > 0.f) ? __float_as_uint(v.x) : 0u;
      u[jj * 4 + 1] = (v.y > 0.f) ? __float_as_uint(v.y) : 0u;
      u[jj * 4 + 2] = (v.z > 0.f) ? __float_as_uint(v.z) : 0u;
      u[jj * 4 + 3] = (v.w > 0.f) ? __float_as_uint(v.w) : 0u;
    }
  }

  __shared__ int red[8];
  unsigned tbits = 0;
  for (int bit = 30; bit >= 0; --bit) {
    unsigned cand = tbits | (1u << bit);
    int c = 0;
#pragma unroll
    for (int j = 0; j < 64; ++j) c += (u[j] >= cand);
#pragma unroll
    for (int off = 32; off > 0; off >>= 1) c += __shfl_down(c, off, 64);
    if ((tid & 63) == 0) red[tid >> 6] = c;
    __syncthreads();
    int tot = red[0] + red[1] + red[2] + red[3];
    __syncthreads();
    if (tot >= k) tbits = cand;
  }

  int cnt_gt = 0, cnt_eq = 0;
  if (tbits != 0) {
    int c1 = 0, c2 = 0;
#pragma unroll
    for (int j = 0; j < 64; ++j) { c1 += (u[j] > tbits); c2 += (u[j] == tbits); }
#pragma unroll
    for (int off = 32; off > 0; off >>= 1) {
      c1 += __shfl_down(c1, off, 64);
      c2 += __shfl_down(c2, off, 64);
    }
    if ((tid & 63) == 0) { red[tid >> 6] = c1; red[4 + (tid >> 6)] = c2; }
    __syncthreads();
    cnt_gt = red[0] + red[1] + red[2] + red[3];
    cnt_eq = red[4] + red[5] + red[6] + red[7];
    __syncthreads();
  }
  const int needed = k - cnt_gt;

  __shared__ int eq_n;
  __shared__ int eq_keep;
  __shared__ int eq_idx[256];
  const bool rare = (tbits != 0) && (cnt_eq > needed);
  if (rare) {
    if (tid == 0) eq_n = 0;
    __syncthreads();
#pragma unroll
    for (int jj = 0; jj < 16; ++jj)
#pragma unroll
      for (int c = 0; c < 4; ++c) {
        int j = jj * 4 + c;
        if (u[j] == tbits) {
          int p = atomicAdd(&eq_n, 1);
          if (p < 256) eq_idx[p] = (tid + jj * 256) * 4 + c;
        }
      }
    __syncthreads();
    if (tid == 0) {
      int n = eq_n < 256 ? eq_n : 256;
      for (int a = 1; a < n; ++a) {
        int key = eq_idx[a]; int b = a - 1;
        while (b >= 0 && eq_idx[b] > key) { eq_idx[b + 1] = eq_idx[b]; --b; }
        eq_idx[b + 1] = key;
      }
      int kp = needed < n ? needed : n;
      eq_keep = kp < 0 ? 0 : kp;
    }
    __syncthreads();
  }

  unsigned long long mask = 0ull;
#pragma unroll
  for (int jj = 0; jj < 16; ++jj)
#pragma unroll
    for (int c = 0; c < 4; ++c) {
      int j = jj * 4 + c;
      bool s;
      if (tbits == 0) {
        s = (u[j] > 0u);
      } else if (u[j] > tbits) {
        s = true;
      } else if (u[j] == tbits) {
        if (!rare) s = true;
        else {
          int idx = (tid + jj * 256) * 4 + c;
          s = false;
          for (int e = 0; e < eq_keep; ++e)
            if (eq_idx[e] == idx) { s = true; break; }
        }
      } else s = false;
      if (s) mask |= (1ull << j);
    }
  const int mycount = __popcll(mask);

  __shared__ int scan[256];
  scan[tid] = mycount;
  __syncthreads();
  for (int off = 1; off < 256; off <<= 1) {
    int v = scan[tid];
    int add = (tid >= off) ? scan[tid - off] : 0;
    __syncthreads();
    scan[tid] = v + add;
    __syncthreads();
  }
  const int total = scan[255];
  int pos = scan[tid] - mycount;

  __shared__ float s_val[1024];
  __shared__ int   s_idx[1024];
  {
    float4* dst = (float4*)zrow;
#pragma unroll
    for (int jj = 0; jj < 16; ++jj) {
      float4 wv;
      float* wp = (float*)&wv;
#pragma unroll
      for (int c = 0; c < 4; ++c) {
        int j = jj * 4 + c;
        bool s = (mask >> j) & 1ull;
        float val = __uint_as_float(u[j]);
        wp[c] = s ? val : 0.f;
        if (s && pos < 1024) {
          s_idx[pos] = (tid + jj * 256) * 4 + c;
          s_val[pos] = val;
          ++pos;
        }
      }
      dst[tid + jj * 256] = wv;
    }
  }
  __syncthreads();

  float a0 = bd[tid], a1 = bd[tid + 256], a2 = bd[tid + 512];
  const int n = total < 1024 ? total : 1024;
#pragma unroll 4
  for (int i = 0; i < n; ++i) {
    float v = s_val[i];
    const float* wr = Wd + (size_t)s_idx[i] * DM;
    a0 = fmaf(v, wr[tid],       a0);
    a1 = fmaf(v, wr[tid + 256], a1);
    a2 = fmaf(v, wr[tid + 512], a2);
  }
  float* rr = recon + (size_t)row * DM;
  rr[tid] = a0; rr[tid + 256] = a1; rr[tid + 512] = a2;
}

// ------------------------------------------------------------------------------
extern "C" void kernel_launch(void* const* d_in, const int* in_sizes, int n_in,
                              void* d_out, int out_size, void* d_ws, size_t ws_size,
                              hipStream_t stream) {
  (void)in_sizes; (void)n_in; (void)out_size;

  const float* x     = (const float*)d_in[0];
  const float* W_enc = (const float*)d_in[1];
  const float* b_enc = (const float*)d_in[2];
  const float* W_dec = (const float*)d_in[3];
  const float* b_dec = (const float*)d_in[4];
  const int*   kp    = (const int*)d_in[5];

  float* z     = (float*)d_out;                    // [NROWS][DS]
  float* recon = z + (size_t)NROWS * DS;           // [NROWS][DM]

  const size_t sz_WTf = (size_t)DS * DM * 4;       // 50,331,648
  const size_t sz_WTb = (size_t)DS * DM * 2;       // 25,165,824
  const size_t sz_xb  = (size_t)NROWS * DM * 2;    // 12,582,912
  const size_t need   = sz_WTf + sz_WTb + sz_xb;   // 88,080,384

  if (ws_size >= need) {
    float*          WTf = (float*)d_ws;
    unsigned short* WTb = (unsigned short*)((char*)d_ws + sz_WTf);
    unsigned short* xb  = (unsigned short*)((char*)d_ws + sz_WTf + sz_WTb);

    cvt_x_bf16<<<(NROWS * DM) / (4 * 256), 256, 0, stream>>>(x, xb);
    transpose_w<<<dim3(DS / 32, DM / 32), 256, 0, stream>>>(W_enc, WTf, WTb);
    sae_encode_bf16<<<dim3(DS / 128, NROWS / 128), 256, 0, stream>>>(xb, WTb, b_enc, z);
    sae_topk_exact<<<NROWS, 256, 0, stream>>>(z, recon, x, WTf, b_enc, W_dec, b_dec, kp);
  } else {
    sae_encode_gemm<<<dim3(DS / BN, NROWS / BM), 256, 0, stream>>>(x, W_enc, b_enc, z);
    sae_topk_decode<<<NROWS, 256, 0, stream>>>(z, recon, W_dec, b_dec, kp);
  }
}